// Round 11
// baseline (31.428 us; speedup 1.0000x reference)
//
#include <hip/hip_runtime.h>
#include <math.h>

#define NPTS 200
#define L33   33
#define L33SQ 1089
#define NLAT  35937        // 33^3
#define NCELL 32768        // 32^3 cells

// ws layout (bytes):
//   [0, 512K)                 H   : bf16 8-corner blocks (NCELL * 16 B)
//   [512K, 512K+143,748)      T   : f32 33^3 combined-logit lattice
//   [next 4B]                 thr : uint bits of max|T| (atomicMax target)
#define WS_T_OFF_BYTES   (NCELL * 16)
#define WS_THR_OFF_BYTES (WS_T_OFF_BYTES + NLAT * 4)

// ---------- trilinear label (channel 0) of grid g at u in [0,R]^3 ----------
template<int R>
__device__ __forceinline__ float tri_label(const float* __restrict__ g,
                                           float ux, float uy, float uz) {
    constexpr int Rp1 = R + 1;
    constexpr int SX  = Rp1 * Rp1;
    int ix = min((int)ux, R - 1);
    int iy = min((int)uy, R - 1);
    int iz = min((int)uz, R - 1);
    float fx = ux - (float)ix, fy = uy - (float)iy, fz = uz - (float)iz;
    int b = (ix * Rp1 + iy) * Rp1 + iz;
    float v000 = g[4*b],            v001 = g[4*(b+1)];
    float v010 = g[4*(b+Rp1)],      v011 = g[4*(b+Rp1+1)];
    float v100 = g[4*(b+SX)],       v101 = g[4*(b+SX+1)];
    float v110 = g[4*(b+SX+Rp1)],   v111 = g[4*(b+SX+Rp1+1)];
    float c00 = fmaf(fz, v001 - v000, v000);
    float c01 = fmaf(fz, v011 - v010, v010);
    float c10 = fmaf(fz, v101 - v100, v100);
    float c11 = fmaf(fz, v111 - v110, v110);
    float c0  = fmaf(fy, c01 - c00, c00);
    float c1  = fmaf(fy, c11 - c10, c10);
    return fmaf(fx, c1 - c0, c0);
}

// ---------- prep1: combined logit at every 33^3 lattice point; init thr ----------
__global__ __launch_bounds__(256)
void prep1_kernel(const float* __restrict__ g0, const float* __restrict__ g1,
                  const float* __restrict__ g2, const float* __restrict__ wl,
                  const float* __restrict__ bl, float* __restrict__ T,
                  unsigned* __restrict__ thrU) {
    int i = blockIdx.x * blockDim.x + threadIdx.x;
    if (i == 0) *thrU = 0u;
    if (i >= NLAT) return;
    int jz = i % L33;
    int r  = i / L33;
    int jy = r % L33;
    int jx = r / L33;
    float fx = (float)jx, fy = (float)jy, fz = (float)jz;
    float L0 = tri_label<8 >(g0, fx * 0.25f, fy * 0.25f, fz * 0.25f);  // exact quarters
    float L1 = tri_label<16>(g1, fx * 0.5f,  fy * 0.5f,  fz * 0.5f);   // exact halves
    float L2 = g2[4 * i];
    T[i] = bl[0] + wl[0] * L0 + wl[1] * L1 + wl[2] * L2;
}

// bf16 RNE: value lands in top 16 bits of r
__device__ __forceinline__ unsigned bf16_rne(float v) {
    unsigned u = __float_as_uint(v);
    return u + 0x7fffu + ((u >> 16) & 1u);
}

// ---------- prep2: one thread per cell -> bf16 8-corner block + global max|T| ----------
// cell = (iy<<10)|(iz<<5)|ix ; words: x={c000,c001} y={c010,c011} z={c100,c101} w={c110,c111}
__global__ __launch_bounds__(256)
void prep2_kernel(const float* __restrict__ T, uint4* __restrict__ H,
                  unsigned* __restrict__ thrU) {
    int cell = blockIdx.x * blockDim.x + threadIdx.x;   // exactly NCELL threads
    int ix = cell & 31;
    int iz = (cell >> 5) & 31;
    int iy = cell >> 10;
    int b = (ix * L33 + iy) * L33 + iz;
    float v000 = T[b],              v001 = T[b + 1];
    float v010 = T[b + L33],        v011 = T[b + L33 + 1];
    float v100 = T[b + L33SQ],      v101 = T[b + L33SQ + 1];
    float v110 = T[b + L33SQ + L33],v111 = T[b + L33SQ + L33 + 1];
    uint4 o;
    o.x = (bf16_rne(v000) >> 16) | (bf16_rne(v001) & 0xffff0000u);
    o.y = (bf16_rne(v010) >> 16) | (bf16_rne(v011) & 0xffff0000u);
    o.z = (bf16_rne(v100) >> 16) | (bf16_rne(v101) & 0xffff0000u);
    o.w = (bf16_rne(v110) >> 16) | (bf16_rne(v111) & 0xffff0000u);
    H[cell] = o;
    float ma = fmaxf(fmaxf(fmaxf(fabsf(v000), fabsf(v001)),
                           fmaxf(fabsf(v010), fabsf(v011))),
                     fmaxf(fmaxf(fabsf(v100), fabsf(v101)),
                           fmaxf(fabsf(v110), fabsf(v111))));
#pragma unroll
    for (int m = 32; m >= 1; m >>= 1)
        ma = fmaxf(ma, __shfl_xor(ma, m, 64));
    if ((threadIdx.x & 63) == 0)
        atomicMax(thrU, __float_as_uint(ma));   // ma >= 0: uint compare == float compare
}

// ---------- RGB corner contribution (1 point per ray, corner-parallel) ----------
template<int R>
__device__ __forceinline__ void rgb_corner(const float* __restrict__ g,
                                           float cx, float cy, float cz,
                                           int dx, int dy, int dz,
                                           float* f3) {
    constexpr int Rp1 = R + 1;
    float ux = cx * (float)R, uy = cy * (float)R, uz = cz * (float)R;
    int ix = min((int)ux, R - 1);
    int iy = min((int)uy, R - 1);
    int iz = min((int)uz, R - 1);
    float fx = ux - (float)ix, fy = uy - (float)iy, fz = uz - (float)iz;
    int idx = ((ix + dx) * Rp1 + (iy + dy)) * Rp1 + (iz + dz);
    float w = (dx ? fx : 1.0f - fx) * (dy ? fy : 1.0f - fy) * (dz ? fz : 1.0f - fz);
    float4 v = *reinterpret_cast<const float4*>(g + 4 * idx);
    f3[0] = w * v.y;
    f3[1] = w * v.z;
    f3[2] = w * v.w;
}

// ---------- main: 16 lanes/ray; ONE 16B bf16 gather per point (4 cells/line);
// 2-compare global-threshold guard; rare f32 pass-2 keeps firsthit exact ----------
__global__ __launch_bounds__(256, 4)
void rays_kernel(const float* __restrict__ x,
                 const uint4* __restrict__ H,
                 const float* __restrict__ T,
                 const unsigned* __restrict__ thrU,
                 const float* __restrict__ g0,
                 const float* __restrict__ g1,
                 const float* __restrict__ g2,
                 const float* __restrict__ wr,
                 const float* __restrict__ br,
                 float* __restrict__ out_hits,
                 float* __restrict__ out_rgb,
                 int n)
{
    const int tid = blockIdx.x * blockDim.x + threadIdx.x;
    const int ray = tid >> 4;
    const int sub = (int)(threadIdx.x & 15);
    if (ray >= n) return;

    const float maxAbs = __uint_as_float(*thrU);
    const float thrG = fmaf(4e-3f, maxAbs, 1e-5f);   // 2x bf16-RNE lerp error bound

    const float th1 = x[ray * 4 + 0];
    const float ph1 = x[ray * 4 + 1];
    const float th2 = x[ray * 4 + 2];
    const float ph2 = x[ray * 4 + 3];
    float s1 = __sinf(th1), c1 = __cosf(th1);
    float s2 = __sinf(th2), c2 = __cosf(th2);
    float p1x = s1 * __cosf(ph1), p1y = s1 * __sinf(ph1), p1z = c1;
    float p2x = s2 * __cosf(ph2), p2y = s2 * __sinf(ph2), p2z = c2;
    const float dxr = p2x - p1x, dyr = p2y - p1y, dzr = p2z - p1z;

    const float inv = 1.0f / (float)(NPTS - 1);
    const float sc  = 16.0f * inv;

    const float bx = fmaf(p1x, 16.0f, 16.0f);
    const float by = fmaf(p1y, 16.0f, 16.0f);
    const float bz = fmaf(p1z, 16.0f, 16.0f);
    const float dux = dxr * sc, duy = dyr * sc, duz = dzr * sc;

    const float subf = (float)sub;
    float maxlogit = -INFINITY;
    unsigned hmask = 0u;   // bit i: certain hit  (logit >  thrG) at t = 16*i + sub
    unsigned smask = 0u;   // bit i: suspect      (|logit| <= thrG)

#define POINT_BODY(I)                                                          \
    {                                                                          \
        float tf = subf + (float)(16 * (I));   /* exact small ints */          \
        float ux = fmaf(tf, dux, bx);                                          \
        float uy = fmaf(tf, duy, by);                                          \
        float uz = fmaf(tf, duz, bz);                                          \
        int ix = min((int)ux, 31);                                             \
        int iy = min((int)uy, 31);                                             \
        int iz = min((int)uz, 31);                                             \
        float fx = ux - (float)ix;                                             \
        float fy = uy - (float)iy;                                             \
        float fz = uz - (float)iz;                                             \
        int cell = (iy << 10) | (iz << 5) | ix;                                \
        uint4 raw = H[cell];                                                   \
        float c000 = __uint_as_float(raw.x << 16);                             \
        float c001 = __uint_as_float(raw.x & 0xffff0000u);                     \
        float c010 = __uint_as_float(raw.y << 16);                             \
        float c011 = __uint_as_float(raw.y & 0xffff0000u);                     \
        float c100 = __uint_as_float(raw.z << 16);                             \
        float c101 = __uint_as_float(raw.z & 0xffff0000u);                     \
        float c110 = __uint_as_float(raw.w << 16);                             \
        float c111 = __uint_as_float(raw.w & 0xffff0000u);                     \
        float b00 = fmaf(fx, c100 - c000, c000);                               \
        float b01 = fmaf(fx, c101 - c001, c001);                               \
        float b10 = fmaf(fx, c110 - c010, c010);                               \
        float b11 = fmaf(fx, c111 - c011, c011);                               \
        float r0 = fmaf(fz, b01 - b00, b00);                                   \
        float r1 = fmaf(fz, b11 - b10, b10);                                   \
        float logit = fmaf(fy, r1 - r0, r0);                                   \
        maxlogit = fmaxf(maxlogit, logit);                                     \
        unsigned bit = 1u << (I);                                              \
        hmask |= (logit > thrG)         ? bit : 0u;                            \
        smask |= (fabsf(logit) <= thrG) ? bit : 0u;                            \
    }

#pragma unroll
    for (int i = 0; i < 12; ++i) POINT_BODY(i)
    if (sub < 8) POINT_BODY(12)          // t = 192..199, half-wave tail
#undef POINT_BODY

    int fc = hmask ? (16 * __builtin_ctz(hmask) + sub) : NPTS;

#pragma unroll
    for (int m = 8; m >= 1; m >>= 1) {
        maxlogit = fmaxf(maxlogit, __shfl_xor(maxlogit, m, 64));
        fc = min(fc, __shfl_xor(fc, m, 64));
    }

    // ---- pass 2 (rare): resolve suspects earlier than the certain first-hit
    // against the f32 lattice (bit-identical to the exact path) ----
    int fh = fc;
    unsigned mm = smask;
    while (mm) {
        int i = __builtin_ctz(mm);
        mm &= mm - 1;
        int t = 16 * i + sub;
        if (t >= fh) break;              // ascending t: nothing else can matter
        float tf = (float)t;
        float ux = fmaf(tf, dux, bx);
        float uy = fmaf(tf, duy, by);
        float uz = fmaf(tf, duz, bz);
        int ix = min((int)ux, 31);
        int iy = min((int)uy, 31);
        int iz = min((int)uz, 31);
        float fx = ux - (float)ix;
        float fy = uy - (float)iy;
        float fz = uz - (float)iz;
        int b = (ix * L33 + iy) * L33 + iz;
        float v000 = T[b],               v001 = T[b + 1];
        float v010 = T[b + L33],         v011 = T[b + L33 + 1];
        float v100 = T[b + L33SQ],       v101 = T[b + L33SQ + 1];
        float v110 = T[b + L33SQ + L33], v111 = T[b + L33SQ + L33 + 1];
        float b00 = fmaf(fx, v100 - v000, v000);
        float b01 = fmaf(fx, v101 - v001, v001);
        float b10 = fmaf(fx, v110 - v010, v010);
        float b11 = fmaf(fx, v111 - v011, v011);
        float r0 = fmaf(fz, b01 - b00, b00);
        float r1 = fmaf(fz, b11 - b10, b10);
        float lg = fmaf(fy, r1 - r0, r0);
        if (lg > 0.0f) { fh = t; break; }
    }

#pragma unroll
    for (int m = 8; m >= 1; m >>= 1)
        fh = min(fh, __shfl_xor(fh, m, 64));

    // ---- RGB at first-hit point: 8 corners across sub&7 (both 8-lane halves
    // compute redundantly; butterfly over m<=4 reduces within each half) ----
    const int tsel = (fh >= NPTS) ? 0 : fh;
    {
        float tt = (float)tsel * inv;
        float px = fmaf(dxr, tt, p1x);
        float py = fmaf(dyr, tt, p1y);
        float pz = fmaf(dzr, tt, p1z);
        float cx = fminf(fmaxf(fmaf(px, 0.5f, 0.5f), 0.0f), 1.0f);
        float cy = fminf(fmaxf(fmaf(py, 0.5f, 0.5f), 0.0f), 1.0f);
        float cz = fminf(fmaxf(fmaf(pz, 0.5f, 0.5f), 0.0f), 1.0f);
        const int s8 = sub & 7;
        const int dx = (s8 >> 2) & 1, dy = (s8 >> 1) & 1, dz = s8 & 1;
        float feat[9];
        rgb_corner<8 >(g0, cx, cy, cz, dx, dy, dz, &feat[0]);
        rgb_corner<16>(g1, cx, cy, cz, dx, dy, dz, &feat[3]);
        rgb_corner<32>(g2, cx, cy, cz, dx, dy, dz, &feat[6]);
        float acc[3];
#pragma unroll
        for (int c = 0; c < 3; ++c) {
            float a = 0.0f;
#pragma unroll
            for (int f = 0; f < 9; ++f) a = fmaf(feat[f], wr[f * 3 + c], a);
            acc[c] = a;
        }
#pragma unroll
        for (int m = 4; m >= 1; m >>= 1) {       // sums the 8 corners per half
#pragma unroll
            for (int c = 0; c < 3; ++c)
                acc[c] += __shfl_xor(acc[c], m, 64);
        }
        if (sub == 0) {
            out_hits[ray] = 1.0f / (1.0f + __expf(-maxlogit));
#pragma unroll
            for (int c = 0; c < 3; ++c)
                out_rgb[ray * 3 + c] = 1.0f / (1.0f + __expf(-(acc[c] + br[c])));
        }
    }
}

extern "C" void kernel_launch(void* const* d_in, const int* in_sizes, int n_in,
                              void* d_out, int out_size, void* d_ws, size_t ws_size,
                              hipStream_t stream) {
    const float* x  = (const float*)d_in[0];
    const float* g0 = (const float*)d_in[1];
    const float* g1 = (const float*)d_in[2];
    const float* g2 = (const float*)d_in[3];
    const float* wl = (const float*)d_in[4];
    const float* bl = (const float*)d_in[5];
    const float* wr = (const float*)d_in[6];
    const float* br = (const float*)d_in[7];

    const int n = in_sizes[0] / 4;
    float* out_hits = (float*)d_out;
    float* out_rgb  = (float*)d_out + n;

    uint4*    H    = (uint4*)d_ws;
    float*    T    = (float*)((char*)d_ws + WS_T_OFF_BYTES);
    unsigned* thrU = (unsigned*)((char*)d_ws + WS_THR_OFF_BYTES);

    prep1_kernel<<<(NLAT + 255) / 256, 256, 0, stream>>>(g0, g1, g2, wl, bl, T, thrU);
    prep2_kernel<<<NCELL / 256, 256, 0, stream>>>(T, H, thrU);

    const int block = 256;             // 16 rays per block
    const int grid = (n * 16 + block - 1) / block;
    rays_kernel<<<grid, block, 0, stream>>>(x, H, T, thrU, g0, g1, g2,
                                            wr, br, out_hits, out_rgb, n);
}

// Round 12
// 21.889 us; speedup vs baseline: 1.4358x; 1.4358x over previous
//
#include <hip/hip_runtime.h>
#include <math.h>

#define NPTS 200
#define L33   33
#define L33SQ 1089
#define NLAT  35937        // 33^3 lattice, f32 = 143,748 B -> dynamic LDS

// ---------- trilinear label (channel 0) of grid g at u in [0,R]^3 ----------
template<int R>
__device__ __forceinline__ float tri_label(const float* __restrict__ g,
                                           float ux, float uy, float uz) {
    constexpr int Rp1 = R + 1;
    constexpr int SX  = Rp1 * Rp1;
    int ix = min((int)ux, R - 1);
    int iy = min((int)uy, R - 1);
    int iz = min((int)uz, R - 1);
    float fx = ux - (float)ix, fy = uy - (float)iy, fz = uz - (float)iz;
    int b = (ix * Rp1 + iy) * Rp1 + iz;
    float v000 = g[4*b],            v001 = g[4*(b+1)];
    float v010 = g[4*(b+Rp1)],      v011 = g[4*(b+Rp1+1)];
    float v100 = g[4*(b+SX)],       v101 = g[4*(b+SX+1)];
    float v110 = g[4*(b+SX+Rp1)],   v111 = g[4*(b+SX+Rp1+1)];
    float c00 = fmaf(fz, v001 - v000, v000);
    float c01 = fmaf(fz, v011 - v010, v010);
    float c10 = fmaf(fz, v101 - v100, v100);
    float c11 = fmaf(fz, v111 - v110, v110);
    float c0  = fmaf(fy, c01 - c00, c00);
    float c1  = fmaf(fy, c11 - c10, c10);
    return fmaf(fx, c1 - c0, c0);
}

// ---------- prep: combined logit at every 33^3 lattice point ----------
__global__ __launch_bounds__(128)
void prep1_kernel(const float* __restrict__ g0, const float* __restrict__ g1,
                  const float* __restrict__ g2, const float* __restrict__ wl,
                  const float* __restrict__ bl, float* __restrict__ T) {
    int i = blockIdx.x * blockDim.x + threadIdx.x;
    if (i >= NLAT) return;
    int jz = i % L33;
    int r  = i / L33;
    int jy = r % L33;
    int jx = r / L33;
    float fx = (float)jx, fy = (float)jy, fz = (float)jz;
    float L0 = tri_label<8 >(g0, fx * 0.25f, fy * 0.25f, fz * 0.25f);  // exact quarters
    float L1 = tri_label<16>(g1, fx * 0.5f,  fy * 0.5f,  fz * 0.5f);   // exact halves
    float L2 = g2[4 * i];
    T[i] = bl[0] + wl[0] * L0 + wl[1] * L1 + wl[2] * L2;
}

// ---------- RGB corner contribution (1 point per ray, corner-parallel) ----------
template<int R>
__device__ __forceinline__ void rgb_corner(const float* __restrict__ g,
                                           float cx, float cy, float cz,
                                           int dx, int dy, int dz,
                                           float* f3) {
    constexpr int Rp1 = R + 1;
    float ux = cx * (float)R, uy = cy * (float)R, uz = cz * (float)R;
    int ix = min((int)ux, R - 1);
    int iy = min((int)uy, R - 1);
    int iz = min((int)uz, R - 1);
    float fx = ux - (float)ix, fy = uy - (float)iy, fz = uz - (float)iz;
    int idx = ((ix + dx) * Rp1 + (iy + dy)) * Rp1 + (iz + dz);
    float w = (dx ? fx : 1.0f - fx) * (dy ? fy : 1.0f - fy) * (dz ? fz : 1.0f - fz);
    float4 v = *reinterpret_cast<const float4*>(g + 4 * idx);
    f3[0] = w * v.y;
    f3[1] = w * v.z;
    f3[2] = w * v.w;
}

// ---------- main: whole 33^3 f32 lattice in LDS; 1024-thread block = 128 rays,
// 8 lanes/ray, 25 full iterations; zero VMEM in the hot loop ----------
__global__ __launch_bounds__(1024, 4)
void rays_kernel(const float* __restrict__ x,
                 const float* __restrict__ T,
                 const float* __restrict__ g0,
                 const float* __restrict__ g1,
                 const float* __restrict__ g2,
                 const float* __restrict__ wr,
                 const float* __restrict__ br,
                 float* __restrict__ out_hits,
                 float* __restrict__ out_rgb)
{
    extern __shared__ float Tl[];        // NLAT floats = 143,748 B
    const int tid = (int)threadIdx.x;

    // stage lattice: coalesced, 36 iterations
    for (int i = tid; i < NLAT; i += 1024) Tl[i] = T[i];
    __syncthreads();

    const int ray = (int)blockIdx.x * 128 + (tid >> 3);   // grid*128 == n exactly
    const int sub = tid & 7;

    const float th1 = x[ray * 4 + 0];
    const float ph1 = x[ray * 4 + 1];
    const float th2 = x[ray * 4 + 2];
    const float ph2 = x[ray * 4 + 3];
    float s1 = __sinf(th1), c1 = __cosf(th1);
    float s2 = __sinf(th2), c2 = __cosf(th2);
    float p1x = s1 * __cosf(ph1), p1y = s1 * __sinf(ph1), p1z = c1;
    float p2x = s2 * __cosf(ph2), p2y = s2 * __sinf(ph2), p2z = c2;
    const float dxr = p2x - p1x, dyr = p2y - p1y, dzr = p2z - p1z;

    const float inv = 1.0f / (float)(NPTS - 1);
    const float sc  = 16.0f * inv;

    const float bx = fmaf(p1x, 16.0f, 16.0f);
    const float by = fmaf(p1y, 16.0f, 16.0f);
    const float bz = fmaf(p1z, 16.0f, 16.0f);
    const float dux = dxr * sc, duy = dyr * sc, duz = dzr * sc;

    const float subf = (float)sub;
    float maxlogit = -INFINITY;
    unsigned hmask = 0u;                 // bit i <-> hit at t = 8*i + sub

#pragma unroll
    for (int i = 0; i < 25; ++i) {
        float tf = subf + (float)(8 * i);    // exact small ints
        float ux = fmaf(tf, dux, bx);
        float uy = fmaf(tf, duy, by);
        float uz = fmaf(tf, duz, bz);
        int ix = min((int)ux, 31);
        int iy = min((int)uy, 31);
        int iz = min((int)uz, 31);
        float fx = ux - (float)ix;
        float fy = uy - (float)iy;
        float fz = uz - (float)iz;
        int b = (ix * L33 + iy) * L33 + iz;
        // 8 corners as 4 z-pairs (compiler merges to ds_read2_b32/b64)
        float v000 = Tl[b],               v001 = Tl[b + 1];
        float v010 = Tl[b + L33],         v011 = Tl[b + L33 + 1];
        float v100 = Tl[b + L33SQ],       v101 = Tl[b + L33SQ + 1];
        float v110 = Tl[b + L33SQ + L33], v111 = Tl[b + L33SQ + L33 + 1];
        float a00 = fmaf(fz, v001 - v000, v000);
        float a01 = fmaf(fz, v011 - v010, v010);
        float a10 = fmaf(fz, v101 - v100, v100);
        float a11 = fmaf(fz, v111 - v110, v110);
        float b0  = fmaf(fy, a01 - a00, a00);
        float b1  = fmaf(fy, a11 - a10, a10);
        float logit = fmaf(fx, b1 - b0, b0);
        maxlogit = fmaxf(maxlogit, logit);
        hmask |= (logit > 0.0f) ? (1u << i) : 0u;
    }

    int fc = hmask ? (8 * __builtin_ctz(hmask) + sub) : NPTS;

#pragma unroll
    for (int m = 4; m >= 1; m >>= 1) {
        maxlogit = fmaxf(maxlogit, __shfl_xor(maxlogit, m, 64));
        fc = min(fc, __shfl_xor(fc, m, 64));
    }

    // ---- RGB at first-hit point, corner-parallel across the 8 lanes ----
    const int tsel = (fc >= NPTS) ? 0 : fc;
    {
        float tt = (float)tsel * inv;
        float px = fmaf(dxr, tt, p1x);
        float py = fmaf(dyr, tt, p1y);
        float pz = fmaf(dzr, tt, p1z);
        float cx = fminf(fmaxf(fmaf(px, 0.5f, 0.5f), 0.0f), 1.0f);
        float cy = fminf(fmaxf(fmaf(py, 0.5f, 0.5f), 0.0f), 1.0f);
        float cz = fminf(fmaxf(fmaf(pz, 0.5f, 0.5f), 0.0f), 1.0f);
        const int dx = (sub >> 2) & 1, dy = (sub >> 1) & 1, dz = sub & 1;
        float feat[9];
        rgb_corner<8 >(g0, cx, cy, cz, dx, dy, dz, &feat[0]);
        rgb_corner<16>(g1, cx, cy, cz, dx, dy, dz, &feat[3]);
        rgb_corner<32>(g2, cx, cy, cz, dx, dy, dz, &feat[6]);
        float acc[3];
#pragma unroll
        for (int c = 0; c < 3; ++c) {
            float a = 0.0f;
#pragma unroll
            for (int f = 0; f < 9; ++f) a = fmaf(feat[f], wr[f * 3 + c], a);
            acc[c] = a;
        }
#pragma unroll
        for (int m = 4; m >= 1; m >>= 1) {       // sums the 8 corners
#pragma unroll
            for (int c = 0; c < 3; ++c)
                acc[c] += __shfl_xor(acc[c], m, 64);
        }
        if (sub == 0) {
            out_hits[ray] = 1.0f / (1.0f + __expf(-maxlogit));
#pragma unroll
            for (int c = 0; c < 3; ++c)
                out_rgb[ray * 3 + c] = 1.0f / (1.0f + __expf(-(acc[c] + br[c])));
        }
    }
}

extern "C" void kernel_launch(void* const* d_in, const int* in_sizes, int n_in,
                              void* d_out, int out_size, void* d_ws, size_t ws_size,
                              hipStream_t stream) {
    const float* x  = (const float*)d_in[0];
    const float* g0 = (const float*)d_in[1];
    const float* g1 = (const float*)d_in[2];
    const float* g2 = (const float*)d_in[3];
    const float* wl = (const float*)d_in[4];
    const float* bl = (const float*)d_in[5];
    const float* wr = (const float*)d_in[6];
    const float* br = (const float*)d_in[7];

    const int n = in_sizes[0] / 4;        // 32768 rays
    float* out_hits = (float*)d_out;
    float* out_rgb  = (float*)d_out + n;

    float* T = (float*)d_ws;              // 143,748 B

    prep1_kernel<<<(NLAT + 127) / 128, 128, 0, stream>>>(g0, g1, g2, wl, bl, T);

    const int grid = n / 128;             // 256 blocks, one per CU, 128 rays each
    rays_kernel<<<grid, 1024, NLAT * sizeof(float), stream>>>(
        x, T, g0, g1, g2, wr, br, out_hits, out_rgb);
}

// Round 13
// 21.736 us; speedup vs baseline: 1.4459x; 1.0070x over previous
//
#include <hip/hip_runtime.h>
#include <math.h>

#define NPTS 200
#define L33   33
#define L33SQ 1089
#define NLAT  35937        // 33^3
#define NPREP (NLAT * 4)

// ws: [0, 575K) Pf pair table (float4 x-adjacent, R5 layout); then T lattice f32
#define WS_T_OFF_FLOATS (NLAT * 4)

// ---------- trilinear label (channel 0) of grid g at u in [0,R]^3 ----------
template<int R>
__device__ __forceinline__ float tri_label(const float* __restrict__ g,
                                           float ux, float uy, float uz) {
    constexpr int Rp1 = R + 1;
    constexpr int SX  = Rp1 * Rp1;
    int ix = min((int)ux, R - 1);
    int iy = min((int)uy, R - 1);
    int iz = min((int)uz, R - 1);
    float fx = ux - (float)ix, fy = uy - (float)iy, fz = uz - (float)iz;
    int b = (ix * Rp1 + iy) * Rp1 + iz;
    float v000 = g[4*b],            v001 = g[4*(b+1)];
    float v010 = g[4*(b+Rp1)],      v011 = g[4*(b+Rp1+1)];
    float v100 = g[4*(b+SX)],       v101 = g[4*(b+SX+1)];
    float v110 = g[4*(b+SX+Rp1)],   v111 = g[4*(b+SX+Rp1+1)];
    float c00 = fmaf(fz, v001 - v000, v000);
    float c01 = fmaf(fz, v011 - v010, v010);
    float c10 = fmaf(fz, v101 - v100, v100);
    float c11 = fmaf(fz, v111 - v110, v110);
    float c0  = fmaf(fy, c01 - c00, c00);
    float c1  = fmaf(fy, c11 - c10, c10);
    return fmaf(fx, c1 - c0, c0);
}

// ---------- prep: Pf pair table (R5 x-adjacent) + T lattice (x-major) ----------
// Pf[4*jj + c], jj = (iy*33 + iz)*33 + ix, c -> (dy,dz); T[(ix*33+iy)*33+iz]
__global__ __launch_bounds__(256)
void prep_kernel(const float* __restrict__ g0, const float* __restrict__ g1,
                 const float* __restrict__ g2, const float* __restrict__ wl,
                 const float* __restrict__ bl, float* __restrict__ Pf,
                 float* __restrict__ T) {
    int id = blockIdx.x * blockDim.x + threadIdx.x;
    if (id >= NPREP) return;
    int c  = id & 3;
    int jj = id >> 2;
    int ix = jj % L33;
    int r  = jj / L33;
    int iz = r % L33;
    int iy = r / L33;
    int jy = min(iy + (c >> 1), L33 - 1);
    int jz = min(iz + (c & 1),  L33 - 1);
    float fx = (float)ix, fy = (float)jy, fz = (float)jz;
    float L0 = tri_label<8 >(g0, fx * 0.25f, fy * 0.25f, fz * 0.25f);  // exact quarters
    float L1 = tri_label<16>(g1, fx * 0.5f,  fy * 0.5f,  fz * 0.5f);   // exact halves
    float L2 = g2[4 * ((ix * L33 + jy) * L33 + jz)];
    float v = bl[0] + wl[0] * L0 + wl[1] * L1 + wl[2] * L2;
    Pf[id] = v;
    if (c == 0) T[(ix * L33 + iy) * L33 + iz] = v;   // same logit at (ix,iy,iz)
}

// ---------- RGB corner contribution (1 point per ray, corner-parallel) ----------
template<int R>
__device__ __forceinline__ void rgb_corner(const float* __restrict__ g,
                                           float cx, float cy, float cz,
                                           int dx, int dy, int dz,
                                           float* f3) {
    constexpr int Rp1 = R + 1;
    float ux = cx * (float)R, uy = cy * (float)R, uz = cz * (float)R;
    int ix = min((int)ux, R - 1);
    int iy = min((int)uy, R - 1);
    int iz = min((int)uz, R - 1);
    float fx = ux - (float)ix, fy = uy - (float)iy, fz = uz - (float)iz;
    int idx = ((ix + dx) * Rp1 + (iy + dy)) * Rp1 + (iz + dz);
    float w = (dx ? fx : 1.0f - fx) * (dy ? fy : 1.0f - fy) * (dz ? fz : 1.0f - fz);
    float4 v = *reinterpret_cast<const float4*>(g + 4 * idx);
    f3[0] = w * v.y;
    f3[1] = w * v.z;
    f3[2] = w * v.w;
}

// ---------- main: dual-pipe hot loop — even iters read LDS lattice (DS pipe),
// odd iters read the global pair table (VMEM pipe); 1024 thr = 128 rays ----------
__global__ __launch_bounds__(1024, 2)   // VGPR cap 128; 16 waves resident (1 blk/CU by LDS)
void rays_kernel(const float* __restrict__ x,
                 const float* __restrict__ T,
                 const float4* __restrict__ P,
                 const float* __restrict__ g0,
                 const float* __restrict__ g1,
                 const float* __restrict__ g2,
                 const float* __restrict__ wr,
                 const float* __restrict__ br,
                 float* __restrict__ out_hits,
                 float* __restrict__ out_rgb)
{
    extern __shared__ float Tl[];        // NLAT floats = 143,748 B
    const int tid = (int)threadIdx.x;

    for (int i = tid; i < NLAT; i += 1024) Tl[i] = T[i];   // coalesced staging
    __syncthreads();

    const int ray = (int)blockIdx.x * 128 + (tid >> 3);
    const int sub = tid & 7;

    const float th1 = x[ray * 4 + 0];
    const float ph1 = x[ray * 4 + 1];
    const float th2 = x[ray * 4 + 2];
    const float ph2 = x[ray * 4 + 3];
    float s1 = __sinf(th1), c1 = __cosf(th1);
    float s2 = __sinf(th2), c2 = __cosf(th2);
    float p1x = s1 * __cosf(ph1), p1y = s1 * __sinf(ph1), p1z = c1;
    float p2x = s2 * __cosf(ph2), p2y = s2 * __sinf(ph2), p2z = c2;
    const float dxr = p2x - p1x, dyr = p2y - p1y, dzr = p2z - p1z;

    const float inv = 1.0f / (float)(NPTS - 1);
    const float sc  = 16.0f * inv;

    const float bx = fmaf(p1x, 16.0f, 16.0f);
    const float by = fmaf(p1y, 16.0f, 16.0f);
    const float bz = fmaf(p1z, 16.0f, 16.0f);
    const float dux = dxr * sc, duy = dyr * sc, duz = dzr * sc;

    const float subf = (float)sub;
    float maxlogit = -INFINITY;
    unsigned hmask = 0u;                 // bit i <-> hit at t = 8*i + sub

#pragma unroll
    for (int i = 0; i < 25; ++i) {
        float tf = subf + (float)(8 * i);    // exact small ints
        float ux = fmaf(tf, dux, bx);
        float uy = fmaf(tf, duy, by);
        float uz = fmaf(tf, duz, bz);
        int ix = min((int)ux, 31);
        int iy = min((int)uy, 31);
        int iz = min((int)uz, 31);
        float fx = ux - (float)ix;
        float fy = uy - (float)iy;
        float fz = uz - (float)iz;
        float logit;
        if ((i & 1) == 0) {
            // DS pipe: 8 corners from LDS lattice (z,y,x lerp)
            int b = (ix * L33 + iy) * L33 + iz;
            float v000 = Tl[b],               v001 = Tl[b + 1];
            float v010 = Tl[b + L33],         v011 = Tl[b + L33 + 1];
            float v100 = Tl[b + L33SQ],       v101 = Tl[b + L33SQ + 1];
            float v110 = Tl[b + L33SQ + L33], v111 = Tl[b + L33SQ + L33 + 1];
            float a00 = fmaf(fz, v001 - v000, v000);
            float a01 = fmaf(fz, v011 - v010, v010);
            float a10 = fmaf(fz, v101 - v100, v100);
            float a11 = fmaf(fz, v111 - v110, v110);
            float b0  = fmaf(fy, a01 - a00, a00);
            float b1  = fmaf(fy, a11 - a10, a10);
            logit = fmaf(fx, b1 - b0, b0);
        } else {
            // VMEM pipe: 2x float4 from the global pair table (x,z,y lerp)
            int jj = (iy * L33 + iz) * L33 + ix;
            const float4* p = P + jj;
            float4 q0 = p[0];
            float4 q1 = p[1];
            float mx = fmaf(fx, q1.x - q0.x, q0.x);
            float my = fmaf(fx, q1.y - q0.y, q0.y);
            float mz = fmaf(fx, q1.z - q0.z, q0.z);
            float mw = fmaf(fx, q1.w - q0.w, q0.w);
            float r0 = fmaf(fz, my - mx, mx);
            float r1 = fmaf(fz, mw - mz, mz);
            logit = fmaf(fy, r1 - r0, r0);
        }
        maxlogit = fmaxf(maxlogit, logit);
        hmask |= (logit > 0.0f) ? (1u << i) : 0u;
    }

    int fc = hmask ? (8 * __builtin_ctz(hmask) + sub) : NPTS;

#pragma unroll
    for (int m = 4; m >= 1; m >>= 1) {
        maxlogit = fmaxf(maxlogit, __shfl_xor(maxlogit, m, 64));
        fc = min(fc, __shfl_xor(fc, m, 64));
    }

    // ---- RGB at first-hit point, corner-parallel across the 8 lanes ----
    const int tsel = (fc >= NPTS) ? 0 : fc;
    {
        float tt = (float)tsel * inv;
        float px = fmaf(dxr, tt, p1x);
        float py = fmaf(dyr, tt, p1y);
        float pz = fmaf(dzr, tt, p1z);
        float cx = fminf(fmaxf(fmaf(px, 0.5f, 0.5f), 0.0f), 1.0f);
        float cy = fminf(fmaxf(fmaf(py, 0.5f, 0.5f), 0.0f), 1.0f);
        float cz = fminf(fmaxf(fmaf(pz, 0.5f, 0.5f), 0.0f), 1.0f);
        const int dx = (sub >> 2) & 1, dy = (sub >> 1) & 1, dz = sub & 1;
        float feat[9];
        rgb_corner<8 >(g0, cx, cy, cz, dx, dy, dz, &feat[0]);
        rgb_corner<16>(g1, cx, cy, cz, dx, dy, dz, &feat[3]);
        rgb_corner<32>(g2, cx, cy, cz, dx, dy, dz, &feat[6]);
        float acc[3];
#pragma unroll
        for (int c = 0; c < 3; ++c) {
            float a = 0.0f;
#pragma unroll
            for (int f = 0; f < 9; ++f) a = fmaf(feat[f], wr[f * 3 + c], a);
            acc[c] = a;
        }
#pragma unroll
        for (int m = 4; m >= 1; m >>= 1) {
#pragma unroll
            for (int c = 0; c < 3; ++c)
                acc[c] += __shfl_xor(acc[c], m, 64);
        }
        if (sub == 0) {
            out_hits[ray] = 1.0f / (1.0f + __expf(-maxlogit));
#pragma unroll
            for (int c = 0; c < 3; ++c)
                out_rgb[ray * 3 + c] = 1.0f / (1.0f + __expf(-(acc[c] + br[c])));
        }
    }
}

extern "C" void kernel_launch(void* const* d_in, const int* in_sizes, int n_in,
                              void* d_out, int out_size, void* d_ws, size_t ws_size,
                              hipStream_t stream) {
    const float* x  = (const float*)d_in[0];
    const float* g0 = (const float*)d_in[1];
    const float* g1 = (const float*)d_in[2];
    const float* g2 = (const float*)d_in[3];
    const float* wl = (const float*)d_in[4];
    const float* bl = (const float*)d_in[5];
    const float* wr = (const float*)d_in[6];
    const float* br = (const float*)d_in[7];

    const int n = in_sizes[0] / 4;        // 32768 rays
    float* out_hits = (float*)d_out;
    float* out_rgb  = (float*)d_out + n;

    float* Pf = (float*)d_ws;                     // 574,992 B pair table
    float* T  = (float*)d_ws + WS_T_OFF_FLOATS;   // 143,748 B lattice

    prep_kernel<<<(NPREP + 255) / 256, 256, 0, stream>>>(g0, g1, g2, wl, bl, Pf, T);

    const int grid = n / 128;             // 256 blocks, 1024 threads, 128 rays each
    rays_kernel<<<grid, 1024, NLAT * sizeof(float), stream>>>(
        x, T, (const float4*)Pf, g0, g1, g2, wr, br, out_hits, out_rgb);
}